// Round 7
// baseline (80.532 us; speedup 1.0000x reference)
//
#include <hip/hip_runtime.h>

#define MAXT 100000.0f

constexpr int B    = 64;
constexpr int IN   = 1024;
constexpr int N    = 1025;   // IN + bias column
constexpr int OUTS = 512;
constexpr int NSEG = 8;      // waves per block (512 threads)
constexpr int NGRP = 16;     // scan groups (half-waves), 64 rows each
constexpr int GRPL = 64;     // rows per group; rank 1024 is group-15 tail
constexpr int JCH  = 32;     // j columns per block
constexpr unsigned KEYMASK = 0xFFFFFC00u;  // top 22 value bits | 10-bit index
constexpr unsigned BIASKEY = 0x3F8003FFu;  // key upper bound for bias rank

struct alignas(8) Pair { unsigned off; unsigned x; };
struct alignas(16) Pair2 { Pair a, b; };   // one ds_read_b128

// ---------------- Fused: per-row sort + gathered-weight scan ----------------
// R13: extend R11's ONLY proven win (independent-block phase overlap,
// 1->2 blocks/CU gave -2.1 us) to 4 blocks/CU. R12's single-read rewrite
// regressed (+3.8: scalar pass-1 loads + VGPR pressure) and is discarded.
// vs R11, unchanged: sort (byte-identical), double-read scan structure
// (float4 pass-1 / scalar pass-2), h-recurrence algebra, atomicMin reduce.
// Changed ONLY: JCH 64->32, grid (64,16) = 1024 blocks -> 4 blocks/CU
// (__launch_bounds__(512,8), kernel is register-light); scan groups are 16
// half-waves x 64 rows -> pass-2 serial chain halves (64 vs 128 rows).
__global__ __launch_bounds__(512, 8) void snn_fused(
    const float* __restrict__ layer_in,
    const float* __restrict__ weight,
    const float* __restrict__ delay,
    float* __restrict__ out) {
  __shared__ unsigned ksh[2][IN];            // double-buffered sort exchange
  __shared__ float vsh[IN];
  __shared__ __align__(16) Pair ps[N + 1];
  __shared__ float2 red2[NGRP][JCH];         // per-group (sum w, sum w*x)
  __shared__ __align__(16) int redm[JCH];    // final min (int bits)

  const int b    = blockIdx.x;
  const int jc   = blockIdx.y;         // 0..15, 32 cols each
  const int lane = threadIdx.x;        // 0..63
  const int seg  = threadIdx.y;        // 0..7 (wave id)
  const int tid  = seg * 64 + lane;
  const int g    = seg * 2 + (lane >> 5);    // scan group 0..15 (half-wave)
  const int c    = lane & 31;                // column within block
  const unsigned jadd = (unsigned)((jc * JCH + c) * 4);   // byte offset

  if (tid < JCH) redm[tid] = __float_as_int(MAXT);  // fenced by sort barriers

  // ---- Phase A: scaled input + 2-elem/thread bitonic argsort (R11 code) ----
  // Thread (lane, seg) owns virtual positions v0 = seg*128+lane (bit6=0) and
  // v1 = v0+64 (bit6=1). Stage (kk,jj): jj<=32 -> shfl; jj==64 -> in-thread;
  // jj>=128 -> LDS (double-buffered, one barrier per round; lds2 fuses pairs).
  {
    const int v0 = seg * 128 + lane;
    const int v1 = v0 + 64;
    float d0 = delay[v0], d1 = delay[v1];
    float x0 = layer_in[b * IN + v0] * expf(d0 > 0.0f ? d0 : 0.0f);
    float x1 = layer_in[b * IN + v1] * expf(d1 > 0.0f ? d1 : 0.0f);
    vsh[v0] = x0; vsh[v1] = x1;
    unsigned k0 = (__float_as_uint(x0) & KEYMASK) | (unsigned)v0;
    unsigned k1 = (__float_as_uint(x1) & KEYMASK) | (unsigned)v1;

    auto sop = [](unsigned x, unsigned y, bool tmin) {
      unsigned mn = x < y ? x : y;
      unsigned mx = x < y ? y : x;
      return tmin ? mn : mx;
    };
    int pb = 0;
    auto shflst = [&](int KK, int JJ) {     // JJ <= 32
      unsigned o0 = __shfl_xor(k0, JJ, 64);
      unsigned o1 = __shfl_xor(k1, JJ, 64);
      k0 = sop(k0, o0, ((v0 & KK) == 0) == ((v0 & JJ) == 0));
      k1 = sop(k1, o1, ((v1 & KK) == 0) == ((v1 & JJ) == 0));
    };
    auto local64 = [&](int KK) {            // jj == 64: partner is in-thread
      bool up = ((v0 & KK) == 0);
      unsigned mn = k0 < k1 ? k0 : k1;
      unsigned mx = k0 < k1 ? k1 : k0;
      k0 = up ? mn : mx;
      k1 = up ? mx : mn;
    };
    auto lds1 = [&](int KK, int JJ) {
      ksh[pb][v0] = k0; ksh[pb][v1] = k1;
      __syncthreads();
      unsigned o0 = ksh[pb][v0 ^ JJ];
      unsigned o1 = ksh[pb][v1 ^ JJ];
      pb ^= 1;
      k0 = sop(k0, o0, ((v0 & KK) == 0) == ((v0 & JJ) == 0));
      k1 = sop(k1, o1, ((v1 & KK) == 0) == ((v1 & JJ) == 0));
    };
    auto lds2 = [&](int KK, int JJ) {       // fused (JJ, JJ/2) stage pair
      int J2 = JJ >> 1;
      ksh[pb][v0] = k0; ksh[pb][v1] = k1;
      __syncthreads();
      {
        unsigned o  = ksh[pb][v0 ^ JJ];
        unsigned a  = ksh[pb][v0 ^ J2];
        unsigned cc = ksh[pb][v0 ^ (JJ | J2)];
        bool up = ((v0 & KK) == 0);
        bool s1 = up == ((v0 & JJ) == 0);
        unsigned kq = sop(k0, o, s1);
        unsigned kp = sop(a, cc, s1);
        k0 = sop(kq, kp, up == ((v0 & J2) == 0));
      }
      {
        unsigned o  = ksh[pb][v1 ^ JJ];
        unsigned a  = ksh[pb][v1 ^ J2];
        unsigned cc = ksh[pb][v1 ^ (JJ | J2)];
        bool up = ((v1 & KK) == 0);
        bool s1 = up == ((v1 & JJ) == 0);
        unsigned kq = sop(k1, o, s1);
        unsigned kp = sop(a, cc, s1);
        k1 = sop(kq, kp, up == ((v1 & J2) == 0));
      }
      pb ^= 1;
    };
    auto tailw = [&](int KK) {              // jj = 32..1
#pragma unroll
      for (int jj = 32; jj > 0; jj >>= 1) shflst(KK, jj);
    };

#pragma unroll
    for (int kk = 2; kk <= 64; kk <<= 1)
#pragma unroll
      for (int jj = kk >> 1; jj > 0; jj >>= 1) shflst(kk, jj);

    local64(128);                       tailw(128);
    lds1(256, 128);   local64(256);     tailw(256);
    lds2(512, 256);   local64(512);     tailw(512);
    lds2(1024, 512);  lds1(1024, 128);  local64(1024);  tailw(1024);

    // bias (x=1.0, idx=IN) rank: elements split across k0/k1 -> two counts
    int r = __syncthreads_count((k0 <= BIASKEY) ? 1 : 0)
          + __syncthreads_count((k1 <= BIASKEY) ? 1 : 0);

    int idx0 = (int)(k0 & 1023u);
    int idx1 = (int)(k1 & 1023u);
    float xs0 = vsh[idx0];
    float xs1 = vsh[idx1];
    int p0 = v0 + (v0 >= r);
    int p1 = v1 + (v1 >= r);
    Pair pr0; pr0.off = (unsigned)(idx0 * OUTS * 4); pr0.x = __float_as_uint(xs0);
    Pair pr1; pr1.off = (unsigned)(idx1 * OUTS * 4); pr1.x = __float_as_uint(xs1);
    ps[p0] = pr0;
    ps[p1] = pr1;
    if (tid == 0) {
      Pair bias; bias.off = (unsigned)(IN * OUTS * 4); bias.x = __float_as_uint(1.0f);
      ps[r] = bias;
      Pair sent; sent.off = 0u; sent.x = __float_as_uint(MAXT);
      ps[N] = sent;
    }
    __syncthreads();
  }

  // ---- Phase B ----
  const char* wbase = (const char*)weight;
  const int is = g * GRPL;

  // Pass 1 (groups 0..14; group 15's total feeds no exclusive prefix):
  // 64 rows x 32 cols per half-wave. quad q = hl&7 -> cols 4q..4q+3
  // (float4); slice sl = hl>>3 takes rows 4uu+sl; combine slices via
  // shfl_xor(8),(16) (both stay inside the 32-lane half).
  if (g < NGRP - 1) {
    const int hl = lane & 31;
    const int q  = hl & 7;
    const int sl = hl >> 3;
    const unsigned jadd4 = (unsigned)((jc * JCH + q * 4) * 4);
    float4 sw = make_float4(0.f, 0.f, 0.f, 0.f);
    float4 sx = make_float4(0.f, 0.f, 0.f, 0.f);
#pragma unroll 8
    for (int uu = 0; uu < 16; ++uu) {
      Pair p = ps[is + 4 * uu + sl];
      float4 w = *(const float4*)(wbase + (p.off + jadd4));
      float xv = __uint_as_float(p.x);
      sw.x += w.x; sw.y += w.y; sw.z += w.z; sw.w += w.w;
      sx.x = fmaf(w.x, xv, sx.x);
      sx.y = fmaf(w.y, xv, sx.y);
      sx.z = fmaf(w.z, xv, sx.z);
      sx.w = fmaf(w.w, xv, sx.w);
    }
#pragma unroll
    for (int d = 8; d <= 16; d <<= 1) {
      sw.x += __shfl_xor(sw.x, d, 64);  sw.y += __shfl_xor(sw.y, d, 64);
      sw.z += __shfl_xor(sw.z, d, 64);  sw.w += __shfl_xor(sw.w, d, 64);
      sx.x += __shfl_xor(sx.x, d, 64);  sx.y += __shfl_xor(sx.y, d, 64);
      sx.z += __shfl_xor(sx.z, d, 64);  sx.w += __shfl_xor(sx.w, d, 64);
    }
    if (sl == 0) {
      red2[g][4 * q + 0] = make_float2(sw.x, sx.x);
      red2[g][4 * q + 1] = make_float2(sw.y, sx.y);
      red2[g][4 * q + 2] = make_float2(sw.z, sx.z);
      red2[g][4 * q + 3] = make_float2(sw.w, sx.w);
    }
  }

  // T14-lite: issue pass-2's first Pair2 + both weight loads, then do the
  // barrier + prefix math under their latency.
  Pair2 t0 = *(const Pair2*)(ps + is);
  float wa = *(const float*)(wbase + (t0.a.off + jadd));
  float wb = *(const float*)(wbase + (t0.b.off + jadd));
  __syncthreads();

  // Exclusive prefix over groups; wc holds w_cum - 1.
  float wc = -1.0f, wi = 0.0f;
  for (int s = 0; s < g; ++s) {
    float2 t = red2[s][c];
    wc += t.x; wi += t.y;
  }

  // Pass 2: 1 col/thread over 64 rows. valid(u) <=> min(wc, -h_prev, h, -bd)
  // >= 0 with h = x_{u+1}*wc - wi (identity g_{u+1} == -h_u exactly); xs
  // sorted => first valid IS the filtered min (R8 algebra, HW-validated).
  float bn = MAXT, bd = -1.0f;
  float xa = __uint_as_float(t0.a.x);
  float xb = __uint_as_float(t0.b.x);
  float hp = fmaf(xa, wc, -wi);

#pragma unroll 4
  for (int u = 0; u < GRPL; u += 2) {
    Pair2 nx = *(const Pair2*)(ps + is + u + 2);   // ds_read_b128, 16-aligned
    float wn1 = *(const float*)(wbase + (nx.a.off + jadd));  // prefetch
    {  // row u: w=wa, xi=xa, xn=xb
      wc += wa; wi = fmaf(wa, xa, wi);
      float h  = fmaf(xb, wc, -wi);
      float qq = fminf(fminf(wc, -hp), fminf(h, -bd));
      bool f = qq >= 0.0f;
      bn = f ? wi : bn;  bd = f ? wc : bd;  hp = h;
    }
    float wn2 = *(const float*)(wbase + (nx.b.off + jadd));  // prefetch
    float xc = __uint_as_float(nx.a.x);
    {  // row u+1: w=wb, xi=xb, xn=xc
      wc += wb; wi = fmaf(wb, xb, wi);
      float h  = fmaf(xc, wc, -wi);
      float qq = fminf(fminf(wc, -hp), fminf(h, -bd));
      bool f = qq >= 0.0f;
      bn = f ? wi : bn;  bd = f ? wc : bd;  hp = h;
    }
    xa = xc; xb = __uint_as_float(nx.b.x); wa = wn1; wb = wn2;
  }
  // Loop exit: wa = weight[row is+64], xa = x[is+64], xb = x[is+65]. For
  // g==15: wa = weight of rank-1024 row, xa = x[1024], xb = MAXT sentinel.
  if (g == NGRP - 1) {
    wc += wa; wi = fmaf(wa, xa, wi);
    float h  = fmaf(xb, wc, -wi);
    float qq = fminf(fminf(wc, -hp), fminf(h, -bd));
    bool f = qq >= 0.0f;
    bn = f ? wi : bn;  bd = f ? wc : bd;
  }
  float best = (bd < 0.0f) ? MAXT : bn * __builtin_amdgcn_rcpf(fmaxf(bd, 1e-10f));

  // Candidates are nonneg floats <= MAXT -> int-bit atomicMin == float min.
  atomicMin(&redm[c], __float_as_int(best));
  __syncthreads();
  if (tid < JCH / 4) {
    int4 mv = *(const int4*)(&redm[tid * 4]);
    float4 o = make_float4(__int_as_float(mv.x), __int_as_float(mv.y),
                           __int_as_float(mv.z), __int_as_float(mv.w));
    *(float4*)(&out[b * OUTS + jc * JCH + tid * 4]) = o;
  }
}

extern "C" void kernel_launch(void* const* d_in, const int* in_sizes, int n_in,
                              void* d_out, int out_size, void* d_ws, size_t ws_size,
                              hipStream_t stream) {
  const float* layer_in = (const float*)d_in[0];
  const float* weight   = (const float*)d_in[1];
  const float* delay    = (const float*)d_in[2];
  float* out = (float*)d_out;
  (void)d_ws; (void)ws_size;

  snn_fused<<<dim3(B, OUTS / JCH), dim3(64, NSEG), 0, stream>>>(
      layer_in, weight, delay, out);
}

// Round 8
// 76.583 us; speedup vs baseline: 1.0516x; 1.0516x over previous
//
#include <hip/hip_runtime.h>

#define MAXT 100000.0f

constexpr int B    = 64;
constexpr int IN   = 1024;
constexpr int N    = 1025;   // IN + bias column
constexpr int OUTS = 512;
constexpr int NSEG = 8;      // segment-waves per block (512 threads)
constexpr int SEGL = 128;    // rows per segment; rank 1024 is seg-7 tail
constexpr int JCH  = 64;     // j columns per block
constexpr unsigned KEYMASK = 0xFFFFFC00u;  // top 22 value bits | 10-bit index
constexpr unsigned BIASKEY = 0x3F8003FFu;  // key upper bound for bias rank

struct alignas(8) Pair { unsigned off; unsigned x; };
struct alignas(16) Pair2 { Pair a, b; };   // one ds_read_b128

// ---------------- Fused: per-row sort + gathered-weight scan ----------------
// R14 = R11 byte-for-byte (best measured: 76.25 us). Session map:
//   1 blk/CU 16w (R10) 78.3 | 2 blk/CU 8w (R11) 76.25 | R12 wreg 80.1 |
//   4 blk/CU (R13) 80.5  -> R11 is a verified local optimum.
// Mechanism that earned the win: two independent 8-wave blocks per CU never
// share a barrier -> memory phases (pass1/2) of one block overlap the
// VALU phases (sort, latch) of the other.
//  * sort: 2 elems/thread (v, v^64): jj=64 thread-local, 4 LDS rounds total
//  * pass 1: segs 0..6 of 128 rows, float4 x 4 row-slices, shfl_xor(16,32)
//  * pass 2: 1 col/thread (light regs), R8 h-recurrence, Pair2 reads,
//    2-deep weight-load pipeline
//  * reduce: LDS atomicMin (int bits of nonneg floats)
__global__ __launch_bounds__(512, 4) void snn_fused(
    const float* __restrict__ layer_in,
    const float* __restrict__ weight,
    const float* __restrict__ delay,
    float* __restrict__ out) {
  __shared__ unsigned ksh[2][IN];            // double-buffered sort exchange
  __shared__ float vsh[IN];
  __shared__ __align__(16) Pair ps[N + 1];
  __shared__ float2 red2[NSEG][JCH];         // per-seg (sum w, sum w*x) per col
  __shared__ __align__(16) int redm[JCH];    // final min (int bits)

  const int b    = blockIdx.x;
  const int jc   = blockIdx.y;         // 0..7, 64 cols each
  const int lane = threadIdx.x;        // 0..63 = col
  const int seg  = threadIdx.y;        // 0..7 (wave id)
  const int tid  = seg * 64 + lane;
  const unsigned jadd = (unsigned)((jc * JCH + lane) * 4);   // byte offset

  if (tid < JCH) redm[tid] = __float_as_int(MAXT);  // fenced by sort barriers

  // ---- Phase A: scaled input + 2-elem/thread bitonic argsort ----
  // Thread (lane, seg) owns virtual positions v0 = seg*128+lane (bit6=0) and
  // v1 = v0+64 (bit6=1). Stage (kk,jj) compare-exchange v <-> v^jj, keep-min
  // iff ((v&kk)==0)==((v&jj)==0):  jj<=32 -> shfl (partner same wave);
  // jj==64 -> between k0,k1 of the SAME thread; jj>=128 -> LDS.
  {
    const int v0 = seg * 128 + lane;
    const int v1 = v0 + 64;
    float d0 = delay[v0], d1 = delay[v1];
    float x0 = layer_in[b * IN + v0] * expf(d0 > 0.0f ? d0 : 0.0f);
    float x1 = layer_in[b * IN + v1] * expf(d1 > 0.0f ? d1 : 0.0f);
    vsh[v0] = x0; vsh[v1] = x1;
    unsigned k0 = (__float_as_uint(x0) & KEYMASK) | (unsigned)v0;
    unsigned k1 = (__float_as_uint(x1) & KEYMASK) | (unsigned)v1;

    auto sop = [](unsigned x, unsigned y, bool tmin) {
      unsigned mn = x < y ? x : y;
      unsigned mx = x < y ? y : x;
      return tmin ? mn : mx;
    };
    int pb = 0;
    auto shflst = [&](int KK, int JJ) {     // JJ <= 32
      unsigned o0 = __shfl_xor(k0, JJ, 64);
      unsigned o1 = __shfl_xor(k1, JJ, 64);
      k0 = sop(k0, o0, ((v0 & KK) == 0) == ((v0 & JJ) == 0));
      k1 = sop(k1, o1, ((v1 & KK) == 0) == ((v1 & JJ) == 0));
    };
    auto local64 = [&](int KK) {            // jj == 64: partner is in-thread
      bool up = ((v0 & KK) == 0);           // KK>=128 -> same flag for v1
      unsigned mn = k0 < k1 ? k0 : k1;
      unsigned mx = k0 < k1 ? k1 : k0;
      k0 = up ? mn : mx;
      k1 = up ? mx : mn;
    };
    // One barrier per LDS round is safe (double buffer): a thread reaches
    // round t+2's write only after round t+1's barrier, which requires all
    // threads past round t's reads.
    auto lds1 = [&](int KK, int JJ) {
      ksh[pb][v0] = k0; ksh[pb][v1] = k1;
      __syncthreads();
      unsigned o0 = ksh[pb][v0 ^ JJ];
      unsigned o1 = ksh[pb][v1 ^ JJ];
      pb ^= 1;
      k0 = sop(k0, o0, ((v0 & KK) == 0) == ((v0 & JJ) == 0));
      k1 = sop(k1, o1, ((v1 & KK) == 0) == ((v1 & JJ) == 0));
    };
    // Fused stage-pair (JJ, JJ/2) in one round-trip (validated R9/R10):
    // partner v^J2 shares stage-JJ flags, so its stage-JJ result is
    // computable from ksh[v^J2] and ksh[v^(JJ|J2)].
    auto lds2 = [&](int KK, int JJ) {
      int J2 = JJ >> 1;
      ksh[pb][v0] = k0; ksh[pb][v1] = k1;
      __syncthreads();
      {
        unsigned o = ksh[pb][v0 ^ JJ];
        unsigned a = ksh[pb][v0 ^ J2];
        unsigned c = ksh[pb][v0 ^ (JJ | J2)];
        bool up = ((v0 & KK) == 0);
        bool s1 = up == ((v0 & JJ) == 0);
        unsigned kq = sop(k0, o, s1);
        unsigned kp = sop(a, c, s1);
        k0 = sop(kq, kp, up == ((v0 & J2) == 0));
      }
      {
        unsigned o = ksh[pb][v1 ^ JJ];
        unsigned a = ksh[pb][v1 ^ J2];
        unsigned c = ksh[pb][v1 ^ (JJ | J2)];
        bool up = ((v1 & KK) == 0);
        bool s1 = up == ((v1 & JJ) == 0);
        unsigned kq = sop(k1, o, s1);
        unsigned kp = sop(a, c, s1);
        k1 = sop(kq, kp, up == ((v1 & J2) == 0));
      }
      pb ^= 1;
    };
    auto tailw = [&](int KK) {              // jj = 32..1
#pragma unroll
      for (int jj = 32; jj > 0; jj >>= 1) shflst(KK, jj);
    };

#pragma unroll
    for (int kk = 2; kk <= 64; kk <<= 1)
#pragma unroll
      for (int jj = kk >> 1; jj > 0; jj >>= 1) shflst(kk, jj);

    local64(128);                       tailw(128);
    lds1(256, 128);   local64(256);     tailw(256);
    lds2(512, 256);   local64(512);     tailw(512);
    lds2(1024, 512);  lds1(1024, 128);  local64(1024);  tailw(1024);

    // bias (x=1.0, idx=IN) rank: elements split across k0/k1 -> two counts
    int r = __syncthreads_count((k0 <= BIASKEY) ? 1 : 0)
          + __syncthreads_count((k1 <= BIASKEY) ? 1 : 0);

    int idx0 = (int)(k0 & 1023u);
    int idx1 = (int)(k1 & 1023u);
    float xs0 = vsh[idx0];
    float xs1 = vsh[idx1];
    int p0 = v0 + (v0 >= r);
    int p1 = v1 + (v1 >= r);
    Pair pr0; pr0.off = (unsigned)(idx0 * OUTS * 4); pr0.x = __float_as_uint(xs0);
    Pair pr1; pr1.off = (unsigned)(idx1 * OUTS * 4); pr1.x = __float_as_uint(xs1);
    ps[p0] = pr0;
    ps[p1] = pr1;
    if (tid == 0) {
      Pair bias; bias.off = (unsigned)(IN * OUTS * 4); bias.x = __float_as_uint(1.0f);
      ps[r] = bias;
      Pair sent; sent.off = 0u; sent.x = __float_as_uint(MAXT);
      ps[N] = sent;
    }
    __syncthreads();
  }

  // ---- Phase B ----
  const char* wbase = (const char*)weight;
  const int is = seg * SEGL;

  // Pass 1 (segs 0..6; seg 7's total feeds no exclusive prefix): 128 rows x
  // 64 cols. quad q = lane&15 -> cols 4q..4q+3 (float4); slice sl = lane>>4
  // takes rows 4uu+sl; combine slices via shfl_xor(16),(32).
  if (seg < NSEG - 1) {
    const int sl = lane >> 4;
    const int q  = lane & 15;
    const unsigned jadd4 = (unsigned)((jc * JCH + q * 4) * 4);
    float4 sw = make_float4(0.f, 0.f, 0.f, 0.f);
    float4 sx = make_float4(0.f, 0.f, 0.f, 0.f);
#pragma unroll 8
    for (int uu = 0; uu < 32; ++uu) {
      Pair p = ps[is + 4 * uu + sl];
      float4 w = *(const float4*)(wbase + (p.off + jadd4));
      float xv = __uint_as_float(p.x);
      sw.x += w.x; sw.y += w.y; sw.z += w.z; sw.w += w.w;
      sx.x = fmaf(w.x, xv, sx.x);
      sx.y = fmaf(w.y, xv, sx.y);
      sx.z = fmaf(w.z, xv, sx.z);
      sx.w = fmaf(w.w, xv, sx.w);
    }
#pragma unroll
    for (int d = 16; d <= 32; d <<= 1) {
      sw.x += __shfl_xor(sw.x, d, 64);  sw.y += __shfl_xor(sw.y, d, 64);
      sw.z += __shfl_xor(sw.z, d, 64);  sw.w += __shfl_xor(sw.w, d, 64);
      sx.x += __shfl_xor(sx.x, d, 64);  sx.y += __shfl_xor(sx.y, d, 64);
      sx.z += __shfl_xor(sx.z, d, 64);  sx.w += __shfl_xor(sx.w, d, 64);
    }
    if (sl == 0) {
      red2[seg][4 * q + 0] = make_float2(sw.x, sx.x);
      red2[seg][4 * q + 1] = make_float2(sw.y, sx.y);
      red2[seg][4 * q + 2] = make_float2(sw.z, sx.z);
      red2[seg][4 * q + 3] = make_float2(sw.w, sx.w);
    }
  }
  __syncthreads();

  // T14-lite: issue pass-2's first Pair2 + both weight loads, then do the
  // prefix math under their latency.
  Pair2 t0 = *(const Pair2*)(ps + is);
  float wa = *(const float*)(wbase + (t0.a.off + jadd));
  float wb = *(const float*)(wbase + (t0.b.off + jadd));

  // Exclusive prefix over segments; wc holds w_cum - 1.
  float wc = -1.0f, wi = 0.0f;
  for (int s = 0; s < seg; ++s) {
    float2 t = red2[s][lane];
    wc += t.x; wi += t.y;
  }

  // Pass 2: 1 col/thread. valid(u) <=> min(wc, -h_prev, h, -bd) >= 0 with
  // h = x_{u+1}*wc - wi (identity g_{u+1} == -h_u exactly); xs sorted =>
  // first valid IS the filtered min (R8 algebra).
  float bn = MAXT, bd = -1.0f;
  float xa = __uint_as_float(t0.a.x);
  float xb = __uint_as_float(t0.b.x);
  float hp = fmaf(xa, wc, -wi);

#pragma unroll 4
  for (int u = 0; u < SEGL; u += 2) {
    Pair2 nx = *(const Pair2*)(ps + is + u + 2);   // ds_read_b128, 16-aligned
    float wn1 = *(const float*)(wbase + (nx.a.off + jadd));  // prefetch
    {  // row u: w=wa, xi=xa, xn=xb
      wc += wa; wi = fmaf(wa, xa, wi);
      float h  = fmaf(xb, wc, -wi);
      float qq = fminf(fminf(wc, -hp), fminf(h, -bd));
      bool f = qq >= 0.0f;
      bn = f ? wi : bn;  bd = f ? wc : bd;  hp = h;
    }
    float wn2 = *(const float*)(wbase + (nx.b.off + jadd));  // prefetch
    float xc = __uint_as_float(nx.a.x);
    {  // row u+1: w=wb, xi=xb, xn=xc
      wc += wb; wi = fmaf(wb, xb, wi);
      float h  = fmaf(xc, wc, -wi);
      float qq = fminf(fminf(wc, -hp), fminf(h, -bd));
      bool f = qq >= 0.0f;
      bn = f ? wi : bn;  bd = f ? wc : bd;  hp = h;
    }
    xa = xc; xb = __uint_as_float(nx.b.x); wa = wn1; wb = wn2;
  }
  if (seg == NSEG - 1) {   // global tail rank 1024; xb = MAXT sentinel
    wc += wa; wi = fmaf(wa, xa, wi);
    float h  = fmaf(xb, wc, -wi);
    float qq = fminf(fminf(wc, -hp), fminf(h, -bd));
    bool f = qq >= 0.0f;
    bn = f ? wi : bn;  bd = f ? wc : bd;
  }
  float best = (bd < 0.0f) ? MAXT : bn * __builtin_amdgcn_rcpf(fmaxf(bd, 1e-10f));

  // Candidates are nonneg floats <= MAXT -> int-bit atomicMin == float min.
  atomicMin(&redm[lane], __float_as_int(best));
  __syncthreads();
  if (tid < JCH / 4) {
    int4 mv = *(const int4*)(&redm[tid * 4]);
    float4 o = make_float4(__int_as_float(mv.x), __int_as_float(mv.y),
                           __int_as_float(mv.z), __int_as_float(mv.w));
    *(float4*)(&out[b * OUTS + jc * JCH + tid * 4]) = o;
  }
}

extern "C" void kernel_launch(void* const* d_in, const int* in_sizes, int n_in,
                              void* d_out, int out_size, void* d_ws, size_t ws_size,
                              hipStream_t stream) {
  const float* layer_in = (const float*)d_in[0];
  const float* weight   = (const float*)d_in[1];
  const float* delay    = (const float*)d_in[2];
  float* out = (float*)d_out;
  (void)d_ws; (void)ws_size;

  snn_fused<<<dim3(B, OUTS / JCH), dim3(64, NSEG), 0, stream>>>(
      layer_in, weight, delay, out);
}